// Round 7
// baseline (791.916 us; speedup 1.0000x reference)
//
#include <hip/hip_runtime.h>
#include <hip/hip_bf16.h>

typedef unsigned u32;
typedef unsigned long long u64;
typedef unsigned short u16;
typedef __bf16 bf16x8 __attribute__((ext_vector_type(8)));
typedef float f32x4 __attribute__((ext_vector_type(4)));
typedef u32 u32x4 __attribute__((ext_vector_type(4)));

// ---- problem shape (all f32) ----
// z: [4,256,32,32] -> M=4096 rows (b*1024+hw), K=256
// codebook: [16384,256] -> N=16384 ; 16 splits of 1024 cols
// out: z_q f32[1048576] then dists f32[512]
// scratch: cand slabs u32[4096][16][16] in d_out z_q region (4 MB, overwritten
// by vq_out); img buffer (256 KiB, consumed first by spherical): bestn@0,
// enorm@16384B.

#define DELTA 2.0f

__device__ __forceinline__ u32 fkey(float f) {
    u32 u = __float_as_uint(f);
    return (u & 0x80000000u) ? ~u : (u | 0x80000000u);
}
__device__ __forceinline__ float unfkey(u32 k) {
    return __uint_as_float((k & 0x80000000u) ? (k & 0x7fffffffu) : ~k);
}

// ---------- spherical distance loss (runs FIRST; consumes img before reuse) ----------
__global__ __launch_bounds__(512) void spherical(const float* __restrict__ img,
                                                 const float* __restrict__ prm,
                                                 float* __restrict__ dout) {
    const int k = threadIdx.x;  // 0..511
    float yv[4], yn2 = 0.f;
#pragma unroll
    for (int b = 0; b < 4; ++b) { yv[b] = prm[b * 512 + k]; yn2 += yv[b] * yv[b]; }
    float yn = fmaxf(sqrtf(yn2), 1e-12f);
#pragma unroll
    for (int b = 0; b < 4; ++b) yv[b] /= yn;
    float acc = 0.f;
    for (int i = 0; i < 32; ++i) {
        float xv[4], xn2 = 0.f;
#pragma unroll
        for (int b = 0; b < 4; ++b) { xv[b] = img[(i * 4 + b) * 512 + k]; xn2 += xv[b] * xv[b]; }
        float xn = fmaxf(sqrtf(xn2), 1e-12f);
        float d2 = 0.f;
#pragma unroll
        for (int b = 0; b < 4; ++b) { float t = xv[b] / xn - yv[b]; d2 += t * t; }
        float d = sqrtf(d2);
        float a = asinf(fminf(0.5f * d, 1.0f));
        acc += 2.0f * a * a;
    }
    dout[k] = acc * (1.0f / 32.0f);
}

// ---------- codebook row norms (f32), one row per thread ----------
__global__ __launch_bounds__(256) void cb_norms(const float* __restrict__ cb,
                                                float* __restrict__ enorm) {
    const int row = blockIdx.x * 256 + threadIdx.x;  // grid 64 -> 16384
    const f32x4* p = (const f32x4*)(cb + (size_t)row * 256);
    float s0 = 0.f, s1 = 0.f, s2 = 0.f, s3 = 0.f;
#pragma unroll 8
    for (int j = 0; j < 64; ++j) {
        f32x4 v = p[j];
        s0 += v[0] * v[0]; s1 += v[1] * v[1];
        s2 += v[2] * v[2]; s3 += v[3] * v[3];
    }
    enorm[row] = (s0 + s1) + (s2 + s3);
}

// ---------- single bf16-MFMA sweep with candidate capture ----------
// grid 1024: split pinned to XCD via bid&7 (2 MB codebook slice per XCD L2).
// Block = 64 M x 1024 N, 4 waves. Register-prefetched B (1 k0-step ahead);
// barrier-free value-only capture epilogue.
__global__ __launch_bounds__(256) void sweep(const float* __restrict__ z,
                                             const float* __restrict__ cb,
                                             const float* __restrict__ enorm,
                                             u32* __restrict__ cand) {
    __shared__ u16 xa[64][264];     // x-tile bf16, [hw][c]
    __shared__ u32 rowmin_s[64];    // fkey(row min), final cross-wave combine
    __shared__ int cnt[64];
    __shared__ u32 candl[64][14];

    const int tid = threadIdx.x;
    const int lane = tid & 63;
    const int w = tid >> 6;
    const int r16 = lane & 15;
    const int kg = lane >> 4;
    const int bid = blockIdx.x;
    const int mtile = bid >> 4;                     // 0..63
    const int r4 = bid & 15;
    const int split = (r4 & 7) * 2 + (r4 >> 3);     // XCD (bid&7) owns {2k,2k+1}
    const int m0 = mtile * 64;
    const int bz = m0 >> 10;
    const int hw0 = m0 & 1023;
    const int nb = split * 1024;

    if (tid < 64) { rowmin_s[tid] = 0xFFFFFFFFu; cnt[tid] = 0; }

    // stage A: z[b][c][hw0..hw0+64) f32 -> xa[hw][c] bf16
    {
        const int c = tid >> 2, hwo = (tid & 3) * 16;
#pragma unroll
        for (int ch = 0; ch < 4; ++ch) {
            const float* src = z + (((size_t)(bz * 256 + ch * 64 + c)) << 10) + hw0 + hwo;
            float vv[16];
            *(f32x4*)&vv[0]  = *(const f32x4*)(src);
            *(f32x4*)&vv[4]  = *(const f32x4*)(src + 4);
            *(f32x4*)&vv[8]  = *(const f32x4*)(src + 8);
            *(f32x4*)&vv[12] = *(const f32x4*)(src + 12);
#pragma unroll
            for (int j = 0; j < 16; ++j) {
                __bf16 h = (__bf16)vv[j];
                xa[hwo + j][ch * 64 + c] = *(const u16*)&h;
            }
        }
    }
    __syncthreads();

    float wmin[4][4];               // per-(mi,r) wave-local running row min
#pragma unroll
    for (int mi = 0; mi < 4; ++mi)
#pragma unroll
        for (int r = 0; r < 4; ++r) wmin[mi][r] = 3.4e38f;

#define LOADB(IT, K0, DST)                                                      \
    {                                                                           \
        const float* p0 = cb + (((size_t)(nb + ((IT) * 4 + w) * 64 + r16)) << 8)\
                          + kg * 8 + (K0) * 32;                                 \
        _Pragma("unroll")                                                       \
        for (int ni_ = 0; ni_ < 4; ++ni_) {                                     \
            DST[ni_ * 2]     = *(const f32x4*)(p0 + (size_t)ni_ * 16 * 256);    \
            DST[ni_ * 2 + 1] = *(const f32x4*)(p0 + (size_t)ni_ * 16 * 256 + 4);\
        }                                                                       \
    }

    f32x4 pb[8];
    LOADB(0, 0, pb);

    for (int it = 0; it < 4; ++it) {
        const int n0 = nb + (it * 4 + w) * 64;
        f32x4 acc[4][4];
#pragma unroll
        for (int mi = 0; mi < 4; ++mi)
#pragma unroll
            for (int ni = 0; ni < 4; ++ni) {
                f32x4 zz = {0.f, 0.f, 0.f, 0.f};
                acc[mi][ni] = zz;
            }
#pragma unroll
        for (int k0 = 0; k0 < 8; ++k0) {
            f32x4 nxt[8];
            if (k0 < 7) {
                LOADB(it, k0 + 1, nxt);
            } else if (it < 3) {
                LOADB(it + 1, 0, nxt);
            }
            bf16x8 fb[4];
#pragma unroll
            for (int ni = 0; ni < 4; ++ni) {
                bf16x8 f;
                f[0] = (__bf16)pb[ni * 2][0]; f[1] = (__bf16)pb[ni * 2][1];
                f[2] = (__bf16)pb[ni * 2][2]; f[3] = (__bf16)pb[ni * 2][3];
                f[4] = (__bf16)pb[ni * 2 + 1][0]; f[5] = (__bf16)pb[ni * 2 + 1][1];
                f[6] = (__bf16)pb[ni * 2 + 1][2]; f[7] = (__bf16)pb[ni * 2 + 1][3];
                fb[ni] = f;
            }
            bf16x8 fa[4];
#pragma unroll
            for (int mi = 0; mi < 4; ++mi)
                fa[mi] = *(const bf16x8*)&xa[r16 + mi * 16][kg * 8 + k0 * 32];
#pragma unroll
            for (int mi = 0; mi < 4; ++mi)
#pragma unroll
                for (int ni = 0; ni < 4; ++ni)
                    acc[mi][ni] = __builtin_amdgcn_mfma_f32_16x16x32_bf16(
                            fa[mi], fb[ni], acc[mi][ni], 0, 0, 0);
#pragma unroll
            for (int q = 0; q < 8; ++q) pb[q] = nxt[q];
        }
        // scores: s = ||e||^2 - 2*dot  (row-constant ||x||^2 dropped)
#pragma unroll
        for (int ni = 0; ni < 4; ++ni) {
            const float en = enorm[n0 + ni * 16 + r16];
#pragma unroll
            for (int mi = 0; mi < 4; ++mi)
#pragma unroll
                for (int r = 0; r < 4; ++r)
                    acc[mi][ni][r] = en - 2.0f * acc[mi][ni][r];
        }
        // barrier-free epilogue: value-only row-min + capture vs wmin+DELTA
#pragma unroll
        for (int mi = 0; mi < 4; ++mi)
#pragma unroll
            for (int r = 0; r < 4; ++r) {
                float v = fminf(fminf(acc[mi][0][r], acc[mi][1][r]),
                                fminf(acc[mi][2][r], acc[mi][3][r]));
#pragma unroll
                for (int d = 1; d < 16; d <<= 1)
                    v = fminf(v, __shfl_xor(v, d));
                const float wm = fminf(wmin[mi][r], v);
                wmin[mi][r] = wm;
                const float thr = wm + DELTA;
                const int ml = mi * 16 + kg * 4 + r;   // D row = (lane>>4)*4+reg
#pragma unroll
                for (int ni = 0; ni < 4; ++ni) {
                    if (acc[mi][ni][r] <= thr) {
                        int pos = atomicAdd(&cnt[ml], 1);
                        if (pos < 14) candl[ml][pos] = (u32)(n0 + ni * 16 + r16);
                    }
                }
            }
    }
#undef LOADB
    // cross-wave row-min combine
    if (r16 == 0) {
#pragma unroll
        for (int mi = 0; mi < 4; ++mi)
#pragma unroll
            for (int r = 0; r < 4; ++r)
                atomicMin(&rowmin_s[mi * 16 + kg * 4 + r], fkey(wmin[mi][r]));
    }
    __syncthreads();
    // write slab [64 rows][16 u32]: {minval, cnt, cand0..cand13}
    {
        const int row_l = tid >> 2, q = tid & 3;
        u32x4 wv;
        if (q == 0) {
            wv[0] = __float_as_uint(unfkey(rowmin_s[row_l]));
            wv[1] = (u32)cnt[row_l];
            wv[2] = candl[row_l][0];
            wv[3] = candl[row_l][1];
        } else {
            const int base = q * 4 - 2;  // 2, 6, 10
            wv[0] = candl[row_l][base];
            wv[1] = candl[row_l][base + 1];
            wv[2] = candl[row_l][base + 2];
            wv[3] = candl[row_l][base + 3];
        }
        u32* dst = cand + ((((size_t)(m0 + row_l)) * 16 + split) << 4) + q * 4;
        *(u32x4*)dst = wv;
    }
}

// ---------- finalize: exact f64 rescore of captured candidates ----------
// grid 1024 x 256: block = 4 rows, one wave per row.
__global__ __launch_bounds__(256) void finalize(const float* __restrict__ z,
                                                const float* __restrict__ cb,
                                                const u32* __restrict__ cand,
                                                u32* __restrict__ bestn) {
    __shared__ u32 slab[4][256];
    const int tid = threadIdx.x;
    const int w = tid >> 6, lane = tid & 63;
    const int row = blockIdx.x * 4 + w;
    const int bz = row >> 10, hw = row & 1023;

    *(u32x4*)&slab[w][lane * 4] = *(const u32x4*)(cand + (size_t)row * 256 + lane * 4);
    float xv[4];
#pragma unroll
    for (int j = 0; j < 4; ++j)
        xv[j] = z[(((size_t)(bz * 256 + lane * 4 + j)) << 10) + hw];
    __syncthreads();

    // global row min over the 16 splits (lane 4s holds split s's minval word)
    float gm = ((lane & 3) == 0) ? __uint_as_float(slab[w][lane * 4]) : 3.4e38f;
#pragma unroll
    for (int d = 1; d < 64; d <<= 1) gm = fminf(gm, __shfl_xor(gm, d));

    double bs = 1e300;
    int bn = 0x7fffffff;
#define RESCORE(NV)                                                         \
    {                                                                       \
        const int n_ = (NV);                                                \
        f32x4 ev = *(const f32x4*)(cb + (((size_t)n_) << 8) + lane * 4);    \
        double t = 0.0;                                                     \
        _Pragma("unroll")                                                   \
        for (int j = 0; j < 4; ++j) {                                       \
            double dl = (double)xv[j] - (double)ev[j];                      \
            t += dl * dl;                                                   \
        }                                                                   \
        _Pragma("unroll")                                                   \
        for (int d = 1; d < 64; d <<= 1) t += __shfl_xor(t, d);             \
        if (t < bs || (t == bs && n_ < bn)) { bs = t; bn = n_; }            \
    }

    for (int s = 0; s < 16; ++s) {
        const float mvs = __uint_as_float(slab[w][s * 16]);
        if (mvs > gm + DELTA) continue;          // no candidate here can win
        const u32 c = slab[w][s * 16 + 1];
        if (c > 14) {
            // capture overflow (rare): exact scan of this split
            for (int n = s * 1024; n < s * 1024 + 1024; ++n) RESCORE(n);
        } else {
            for (u32 ci = 0; ci < c; ++ci) RESCORE((int)slab[w][s * 16 + 2 + ci]);
        }
    }
#undef RESCORE
    if (lane == 0) bestn[row] = (u32)bn;
}

// ---------- gather selected codebook rows (f32) into channel-first out ----------
__global__ __launch_bounds__(256) void vq_out(const u32* __restrict__ bestn,
                                              const float* __restrict__ cb,
                                              float* __restrict__ out) {
    __shared__ float rows_l[64][133];
    __shared__ int idx_s[64];
    const int tid = threadIdx.x;
    const int hwt = blockIdx.x, b = blockIdx.y;
    const int m0 = b * 1024 + hwt * 64;
    if (tid < 64) idx_s[tid] = (int)bestn[m0 + tid];
    __syncthreads();
    const int lane = tid & 63, w = tid >> 6;
#pragma unroll
    for (int half = 0; half < 2; ++half) {
        const int row = tid >> 2, q = tid & 3;
        const float* src = cb + (((size_t)idx_s[row]) << 8) + half * 128 + q * 32;
#pragma unroll
        for (int j = 0; j < 8; ++j)
            *(f32x4*)&rows_l[row][q * 32 + j * 4] = *(const f32x4*)(src + j * 4);
        __syncthreads();
#pragma unroll
        for (int i = 0; i < 32; ++i) {
            const int c = half * 128 + w * 32 + i;
            out[(((size_t)(b * 256 + c)) << 10) + hwt * 64 + lane] = rows_l[lane][w * 32 + i];
        }
        __syncthreads();
    }
}

extern "C" void kernel_launch(void* const* d_in, const int* in_sizes, int n_in,
                              void* d_out, int out_size, void* d_ws, size_t ws_size,
                              hipStream_t stream) {
    const float* z   = (const float*)d_in[0];
    const float* cb  = (const float*)d_in[1];
    const float* img = (const float*)d_in[2];
    const float* prm = (const float*)d_in[3];
    float* out = (float*)d_out;

    // img buffer reused as small scratch after spherical consumes it.
    char* scr = (char*)d_in[2];
    u32* bestn = (u32*)scr;                   // 16 KiB
    float* enorm = (float*)(scr + 16384);     // 64 KiB
    u32* cand = (u32*)d_out;                  // 4 MiB slabs, overwritten by vq_out

    spherical<<<1, 512, 0, stream>>>(img, prm, out + 1048576);
    cb_norms<<<64, 256, 0, stream>>>(cb, enorm);
    sweep<<<1024, 256, 0, stream>>>(z, cb, enorm, cand);
    finalize<<<1024, 256, 0, stream>>>(z, cb, cand, bestn);
    vq_out<<<dim3(16, 4), 256, 0, stream>>>(bestn, cb, out);
}

// Round 8
// 258.604 us; speedup vs baseline: 3.0623x; 3.0623x over previous
//
#include <hip/hip_runtime.h>
#include <hip/hip_bf16.h>

typedef unsigned u32;
typedef unsigned long long u64;
typedef unsigned short u16;
typedef __bf16 bf16x8 __attribute__((ext_vector_type(8)));
typedef float f32x4 __attribute__((ext_vector_type(4)));
typedef u32 u32x4 __attribute__((ext_vector_type(4)));

// ---- problem shape (all f32) ----
// z: [4,256,32,32] -> M=4096 rows (b*1024+hw), K=256
// codebook: [16384,256] -> N=16384 ; 16 splits of 1024 cols
// out: z_q f32[1048576] then dists f32[512]
// scratch: cand slabs u32[4096][16][16] in d_out z_q region (4 MB, overwritten
// by vq_out); img buffer (256 KiB, consumed first by spherical): bestn@0,
// enorm@16384B.

#define DELTA 2.0f

__device__ __forceinline__ u32 fkey(float f) {
    u32 u = __float_as_uint(f);
    return (u & 0x80000000u) ? ~u : (u | 0x80000000u);
}
__device__ __forceinline__ float unfkey(u32 k) {
    return __uint_as_float((k & 0x80000000u) ? (k & 0x7fffffffu) : ~k);
}

// ---------- spherical distance loss (runs FIRST; consumes img before reuse) ----------
__global__ __launch_bounds__(512) void spherical(const float* __restrict__ img,
                                                 const float* __restrict__ prm,
                                                 float* __restrict__ dout) {
    const int k = threadIdx.x;  // 0..511
    float yv[4], yn2 = 0.f;
#pragma unroll
    for (int b = 0; b < 4; ++b) { yv[b] = prm[b * 512 + k]; yn2 += yv[b] * yv[b]; }
    float yn = fmaxf(sqrtf(yn2), 1e-12f);
#pragma unroll
    for (int b = 0; b < 4; ++b) yv[b] /= yn;
    float acc = 0.f;
    for (int i = 0; i < 32; ++i) {
        float xv[4], xn2 = 0.f;
#pragma unroll
        for (int b = 0; b < 4; ++b) { xv[b] = img[(i * 4 + b) * 512 + k]; xn2 += xv[b] * xv[b]; }
        float xn = fmaxf(sqrtf(xn2), 1e-12f);
        float d2 = 0.f;
#pragma unroll
        for (int b = 0; b < 4; ++b) { float t = xv[b] / xn - yv[b]; d2 += t * t; }
        float d = sqrtf(d2);
        float a = asinf(fminf(0.5f * d, 1.0f));
        acc += 2.0f * a * a;
    }
    dout[k] = acc * (1.0f / 32.0f);
}

// ---------- codebook row norms (f32), one row per thread ----------
__global__ __launch_bounds__(256) void cb_norms(const float* __restrict__ cb,
                                                float* __restrict__ enorm) {
    const int row = blockIdx.x * 256 + threadIdx.x;  // grid 64 -> 16384
    const f32x4* p = (const f32x4*)(cb + (size_t)row * 256);
    float s0 = 0.f, s1 = 0.f, s2 = 0.f, s3 = 0.f;
#pragma unroll 8
    for (int j = 0; j < 64; ++j) {
        f32x4 v = p[j];
        s0 += v[0] * v[0]; s1 += v[1] * v[1];
        s2 += v[2] * v[2]; s3 += v[3] * v[3];
    }
    enorm[row] = (s0 + s1) + (s2 + s3);
}

// ---------- single bf16-MFMA sweep with candidate capture ----------
// grid 1024: split pinned to XCD via bid&7 (2 MB codebook slice per XCD L2).
// Block = 64 M x 1024 N, 4 waves. Static ping-pong register double-buffer for
// B (bufA/bufB, no copies); cross-wave LDS rowmin keeps capture tight.
__global__ __launch_bounds__(256) void sweep(const float* __restrict__ z,
                                             const float* __restrict__ cb,
                                             const float* __restrict__ enorm,
                                             u32* __restrict__ cand) {
    __shared__ u16 xa[64][264];     // x-tile bf16, [hw][c]
    __shared__ u32 rowmin_s[64];    // fkey(running row min), cross-wave
    __shared__ int cnt[64];
    __shared__ u32 candl[64][14];

    const int tid = threadIdx.x;
    const int lane = tid & 63;
    const int w = tid >> 6;
    const int r16 = lane & 15;
    const int kg = lane >> 4;
    const int bid = blockIdx.x;
    const int mtile = bid >> 4;                     // 0..63
    const int r4 = bid & 15;
    const int split = (r4 & 7) * 2 + (r4 >> 3);     // XCD (bid&7) owns {2k,2k+1}
    const int m0 = mtile * 64;
    const int bz = m0 >> 10;
    const int hw0 = m0 & 1023;
    const int nb = split * 1024;

    if (tid < 64) { rowmin_s[tid] = 0xFFFFFFFFu; cnt[tid] = 0; }

    // stage A: z[b][c][hw0..hw0+64) f32 -> xa[hw][c] bf16
    {
        const int c = tid >> 2, hwo = (tid & 3) * 16;
#pragma unroll
        for (int ch = 0; ch < 4; ++ch) {
            const float* src = z + (((size_t)(bz * 256 + ch * 64 + c)) << 10) + hw0 + hwo;
            float vv[16];
            *(f32x4*)&vv[0]  = *(const f32x4*)(src);
            *(f32x4*)&vv[4]  = *(const f32x4*)(src + 4);
            *(f32x4*)&vv[8]  = *(const f32x4*)(src + 8);
            *(f32x4*)&vv[12] = *(const f32x4*)(src + 12);
#pragma unroll
            for (int j = 0; j < 16; ++j) {
                __bf16 h = (__bf16)vv[j];
                xa[hwo + j][ch * 64 + c] = *(const u16*)&h;
            }
        }
    }
    __syncthreads();

    float wmin[4][4];               // per-(mi,r) wave-local running row min
#pragma unroll
    for (int mi = 0; mi < 4; ++mi)
#pragma unroll
        for (int r = 0; r < 4; ++r) wmin[mi][r] = 3.4e38f;

    // B loads for flat step S (tile S>>3, k-chunk S&7), 8x f32x4 per step
#define LOADB(S, DST)                                                           \
    {                                                                           \
        const int s_ = (S);                                                     \
        const float* p0 = cb                                                    \
            + (((size_t)(nb + ((s_ >> 3) * 4 + w) * 64 + r16)) << 8)            \
            + kg * 8 + (s_ & 7) * 32;                                           \
        _Pragma("unroll")                                                       \
        for (int ni_ = 0; ni_ < 4; ++ni_) {                                     \
            DST[ni_ * 2]     = *(const f32x4*)(p0 + (size_t)ni_ * 4096);        \
            DST[ni_ * 2 + 1] = *(const f32x4*)(p0 + (size_t)ni_ * 4096 + 4);    \
        }                                                                       \
    }

#define COMPUTE(BUF)                                                            \
    {                                                                           \
        bf16x8 fb[4];                                                           \
        _Pragma("unroll")                                                       \
        for (int ni_ = 0; ni_ < 4; ++ni_) {                                     \
            bf16x8 f;                                                           \
            f[0] = (__bf16)BUF[ni_ * 2][0]; f[1] = (__bf16)BUF[ni_ * 2][1];     \
            f[2] = (__bf16)BUF[ni_ * 2][2]; f[3] = (__bf16)BUF[ni_ * 2][3];     \
            f[4] = (__bf16)BUF[ni_ * 2 + 1][0]; f[5] = (__bf16)BUF[ni_ * 2 + 1][1]; \
            f[6] = (__bf16)BUF[ni_ * 2 + 1][2]; f[7] = (__bf16)BUF[ni_ * 2 + 1][3]; \
            fb[ni_] = f;                                                        \
        }                                                                       \
        bf16x8 fa[4];                                                           \
        _Pragma("unroll")                                                       \
        for (int mi_ = 0; mi_ < 4; ++mi_)                                       \
            fa[mi_] = *(const bf16x8*)&xa[r16 + mi_ * 16][kg * 8 + k0 * 32];    \
        _Pragma("unroll")                                                       \
        for (int mi_ = 0; mi_ < 4; ++mi_)                                       \
            _Pragma("unroll")                                                   \
            for (int ni_ = 0; ni_ < 4; ++ni_)                                   \
                acc[mi_][ni_] = __builtin_amdgcn_mfma_f32_16x16x32_bf16(        \
                        fa[mi_], fb[ni_], acc[mi_][ni_], 0, 0, 0);              \
    }

    f32x4 bufA[8], bufB[8];
    LOADB(0, bufA);

    for (int it = 0; it < 4; ++it) {
        const int n0 = nb + (it * 4 + w) * 64;
        f32x4 acc[4][4];
#pragma unroll
        for (int mi = 0; mi < 4; ++mi)
#pragma unroll
            for (int ni = 0; ni < 4; ++ni) {
                f32x4 zz = {0.f, 0.f, 0.f, 0.f};
                acc[mi][ni] = zz;
            }
#pragma unroll
        for (int k0 = 0; k0 < 8; ++k0) {
            const int s = it * 8 + k0;
            if ((k0 & 1) == 0) {
                if (s < 31) LOADB(s + 1, bufB);
                __builtin_amdgcn_sched_barrier(0);   // pin prefetch before compute
                COMPUTE(bufA);
            } else {
                if (s < 31) LOADB(s + 1, bufA);
                __builtin_amdgcn_sched_barrier(0);
                COMPUTE(bufB);
            }
        }
        // scores: s = ||e||^2 - 2*dot  (row-constant ||x||^2 dropped)
#pragma unroll
        for (int ni = 0; ni < 4; ++ni) {
            const float en = enorm[n0 + ni * 16 + r16];
#pragma unroll
            for (int mi = 0; mi < 4; ++mi)
#pragma unroll
                for (int r = 0; r < 4; ++r)
                    acc[mi][ni][r] = en - 2.0f * acc[mi][ni][r];
        }
        // tile min -> publish to cross-wave LDS rowmin (no barrier needed:
        // running mins only decrease, so thresholds remain a safe superset)
#pragma unroll
        for (int mi = 0; mi < 4; ++mi)
#pragma unroll
            for (int r = 0; r < 4; ++r) {
                float v = fminf(fminf(acc[mi][0][r], acc[mi][1][r]),
                                fminf(acc[mi][2][r], acc[mi][3][r]));
#pragma unroll
                for (int d = 1; d < 16; d <<= 1)
                    v = fminf(v, __shfl_xor(v, d));
                const float wm = fminf(wmin[mi][r], v);
                wmin[mi][r] = wm;
                if (r16 == 0)
                    atomicMin(&rowmin_s[mi * 16 + kg * 4 + r], fkey(wm));
            }
        // capture vs min(shared rowmin, own) + DELTA
#pragma unroll
        for (int mi = 0; mi < 4; ++mi)
#pragma unroll
            for (int r = 0; r < 4; ++r) {
                const int ml = mi * 16 + kg * 4 + r;   // D row = (lane>>4)*4+reg
                const float thr = fminf(unfkey(rowmin_s[ml]), wmin[mi][r]) + DELTA;
#pragma unroll
                for (int ni = 0; ni < 4; ++ni) {
                    if (acc[mi][ni][r] <= thr) {
                        int pos = atomicAdd(&cnt[ml], 1);
                        if (pos < 14) candl[ml][pos] = (u32)(n0 + ni * 16 + r16);
                    }
                }
            }
    }
#undef LOADB
#undef COMPUTE
    __syncthreads();
    // write slab [64 rows][16 u32]: {minval, cnt, cand0..cand13}
    {
        const int row_l = tid >> 2, q = tid & 3;
        u32x4 wv;
        if (q == 0) {
            wv[0] = __float_as_uint(unfkey(rowmin_s[row_l]));
            wv[1] = (u32)cnt[row_l];
            wv[2] = candl[row_l][0];
            wv[3] = candl[row_l][1];
        } else {
            const int base = q * 4 - 2;  // 2, 6, 10
            wv[0] = candl[row_l][base];
            wv[1] = candl[row_l][base + 1];
            wv[2] = candl[row_l][base + 2];
            wv[3] = candl[row_l][base + 3];
        }
        u32* dst = cand + ((((size_t)(m0 + row_l)) * 16 + split) << 4) + q * 4;
        *(u32x4*)dst = wv;
    }
}

// ---------- finalize: exact f64 rescore of captured candidates ----------
// grid 1024 x 256: block = 4 rows, one wave per row.
__global__ __launch_bounds__(256) void finalize(const float* __restrict__ z,
                                                const float* __restrict__ cb,
                                                const u32* __restrict__ cand,
                                                u32* __restrict__ bestn) {
    __shared__ u32 slab[4][256];
    const int tid = threadIdx.x;
    const int w = tid >> 6, lane = tid & 63;
    const int row = blockIdx.x * 4 + w;
    const int bz = row >> 10, hw = row & 1023;

    *(u32x4*)&slab[w][lane * 4] = *(const u32x4*)(cand + (size_t)row * 256 + lane * 4);
    float xv[4];
#pragma unroll
    for (int j = 0; j < 4; ++j)
        xv[j] = z[(((size_t)(bz * 256 + lane * 4 + j)) << 10) + hw];
    __syncthreads();

    // global row min over the 16 splits (lane 4s holds split s's minval word)
    float gm = ((lane & 3) == 0) ? __uint_as_float(slab[w][lane * 4]) : 3.4e38f;
#pragma unroll
    for (int d = 1; d < 64; d <<= 1) gm = fminf(gm, __shfl_xor(gm, d));

    double bs = 1e300;
    int bn = 0x7fffffff;
#define RESCORE(NV)                                                         \
    {                                                                       \
        const int n_ = (NV);                                                \
        f32x4 ev = *(const f32x4*)(cb + (((size_t)n_) << 8) + lane * 4);    \
        double t = 0.0;                                                     \
        _Pragma("unroll")                                                   \
        for (int j = 0; j < 4; ++j) {                                       \
            double dl = (double)xv[j] - (double)ev[j];                      \
            t += dl * dl;                                                   \
        }                                                                   \
        _Pragma("unroll")                                                   \
        for (int d = 1; d < 64; d <<= 1) t += __shfl_xor(t, d);             \
        if (t < bs || (t == bs && n_ < bn)) { bs = t; bn = n_; }            \
    }

    for (int s = 0; s < 16; ++s) {
        const float mvs = __uint_as_float(slab[w][s * 16]);
        if (mvs > gm + DELTA) continue;          // no candidate here can win
        const u32 c = slab[w][s * 16 + 1];
        if (c > 14) {
            // capture overflow (rare): exact scan of this split
            for (int n = s * 1024; n < s * 1024 + 1024; ++n) RESCORE(n);
        } else {
            for (u32 ci = 0; ci < c; ++ci) RESCORE((int)slab[w][s * 16 + 2 + ci]);
        }
    }
#undef RESCORE
    if (lane == 0) bestn[row] = (u32)bn;
}

// ---------- gather selected codebook rows (f32) into channel-first out ----------
__global__ __launch_bounds__(256) void vq_out(const u32* __restrict__ bestn,
                                              const float* __restrict__ cb,
                                              float* __restrict__ out) {
    __shared__ float rows_l[64][133];
    __shared__ int idx_s[64];
    const int tid = threadIdx.x;
    const int hwt = blockIdx.x, b = blockIdx.y;
    const int m0 = b * 1024 + hwt * 64;
    if (tid < 64) idx_s[tid] = (int)bestn[m0 + tid];
    __syncthreads();
    const int lane = tid & 63, w = tid >> 6;
#pragma unroll
    for (int half = 0; half < 2; ++half) {
        const int row = tid >> 2, q = tid & 3;
        const float* src = cb + (((size_t)idx_s[row]) << 8) + half * 128 + q * 32;
#pragma unroll
        for (int j = 0; j < 8; ++j)
            *(f32x4*)&rows_l[row][q * 32 + j * 4] = *(const f32x4*)(src + j * 4);
        __syncthreads();
#pragma unroll
        for (int i = 0; i < 32; ++i) {
            const int c = half * 128 + w * 32 + i;
            out[(((size_t)(b * 256 + c)) << 10) + hwt * 64 + lane] = rows_l[lane][w * 32 + i];
        }
        __syncthreads();
    }
}

extern "C" void kernel_launch(void* const* d_in, const int* in_sizes, int n_in,
                              void* d_out, int out_size, void* d_ws, size_t ws_size,
                              hipStream_t stream) {
    const float* z   = (const float*)d_in[0];
    const float* cb  = (const float*)d_in[1];
    const float* img = (const float*)d_in[2];
    const float* prm = (const float*)d_in[3];
    float* out = (float*)d_out;

    // img buffer reused as small scratch after spherical consumes it.
    char* scr = (char*)d_in[2];
    u32* bestn = (u32*)scr;                   // 16 KiB
    float* enorm = (float*)(scr + 16384);     // 64 KiB
    u32* cand = (u32*)d_out;                  // 4 MiB slabs, overwritten by vq_out

    spherical<<<1, 512, 0, stream>>>(img, prm, out + 1048576);
    cb_norms<<<64, 256, 0, stream>>>(cb, enorm);
    sweep<<<1024, 256, 0, stream>>>(z, cb, enorm, cand);
    finalize<<<1024, 256, 0, stream>>>(z, cb, cand, bestn);
    vq_out<<<dim3(16, 4), 256, 0, stream>>>(bestn, cb, out);
}

// Round 10
// 217.001 us; speedup vs baseline: 3.6494x; 1.1917x over previous
//
#include <hip/hip_runtime.h>
#include <hip/hip_bf16.h>

typedef unsigned u32;
typedef unsigned short u16;
typedef __bf16 bf16x8 __attribute__((ext_vector_type(8)));
typedef float f32x4 __attribute__((ext_vector_type(4)));
typedef u32 u32x4 __attribute__((ext_vector_type(4)));

// ---- problem shape (all f32) ----
// z: [4,256,32,32] -> M=4096 rows (b*1024+hw), K=256
// codebook: [16384,256] -> N=16384 ; 8 splits of 2048 cols (one per XCD)
// out: z_q f32[1048576] then dists f32[512]
// scratch: cand slabs u32[4096][8][16] (2 MB) in d_out z_q region (overwritten
// by vq_out); img buffer: bestn u32[4096]@0 (written by finalize AFTER
// spherical has consumed img).

#define DELTA 2.0f

__device__ __forceinline__ u32 fkey(float f) {
    u32 u = __float_as_uint(f);
    return (u & 0x80000000u) ? ~u : (u | 0x80000000u);
}
__device__ __forceinline__ float unfkey(u32 k) {
    return __uint_as_float((k & 0x80000000u) ? (k & 0x7fffffffu) : ~k);
}

typedef __attribute__((address_space(1))) const float glb_f;
typedef __attribute__((address_space(3))) float lds_f;

// ---------- spherical distance loss, parallel over cuts ----------
// grid 32 (one block per cut), 512 thr (one per emb col). dout pre-zeroed.
__global__ __launch_bounds__(512) void spherical_i(const float* __restrict__ img,
                                                   const float* __restrict__ prm,
                                                   float* __restrict__ dout) {
    const int i = blockIdx.x, k = threadIdx.x;
    float yv[4], yn2 = 0.f;
#pragma unroll
    for (int b = 0; b < 4; ++b) { yv[b] = prm[b * 512 + k]; yn2 += yv[b] * yv[b]; }
    float yn = fmaxf(sqrtf(yn2), 1e-12f);
    float xv[4], xn2 = 0.f;
#pragma unroll
    for (int b = 0; b < 4; ++b) { xv[b] = img[(i * 4 + b) * 512 + k]; xn2 += xv[b] * xv[b]; }
    float xn = fmaxf(sqrtf(xn2), 1e-12f);
    float d2 = 0.f;
#pragma unroll
    for (int b = 0; b < 4; ++b) { float t = xv[b] / xn - yv[b] / yn; d2 += t * t; }
    float d = sqrtf(d2);
    float a = asinf(fminf(0.5f * d, 1.0f));
    atomicAdd(&dout[k], (2.0f * a * a) * (1.0f / 32.0f));
}

// ---------- bf16-MFMA sweep: B via global_load_lds 2-phase, fused ||e||^2 ----------
// grid 512: split = bid&7 pinned to XCD (2 MB codebook slice L2-resident).
// Block = 64 M x 2048 N (8 tiles of 256 rows), 4 waves. Per 32-k chunk:
// barrier -> stage 32KB to LDS (linear dest, pre-swizzled source) -> barrier
// (compiler drains vmcnt) -> swizzled ds_read_b128 + cvt + 16 MFMA.
__global__ __launch_bounds__(256, 2) void sweep(const float* __restrict__ z,
                                                const float* __restrict__ cb,
                                                u32* __restrict__ cand) {
    __shared__ u16 xa[64][264];     // x-tile bf16, [hw][c]   (33792 B)
    __shared__ float bsf[8192];     // B chunk [256 rows][32 f], read-swizzled (32 KiB)
    __shared__ u32 rowmin_s[64];
    __shared__ int cnt[64];
    __shared__ u32 candl[64][14];

    const int tid = threadIdx.x;
    const int lane = tid & 63;
    const int w = tid >> 6;
    const int r16 = lane & 15;
    const int kg = lane >> 4;
    const int bid = blockIdx.x;
    const int split = bid & 7;      // XCD id under round-robin dispatch
    const int mtile = bid >> 3;     // 0..63
    const int m0 = mtile * 64;
    const int bz = m0 >> 10;
    const int hw0 = m0 & 1023;
    const int nb = split * 2048;

    if (tid < 64) { rowmin_s[tid] = 0xFFFFFFFFu; cnt[tid] = 0; }

    // stage A: z[b][c][hw0..hw0+64) f32 -> xa[hw][c] bf16
    {
        const int c = tid >> 2, hwo = (tid & 3) * 16;
#pragma unroll
        for (int ch = 0; ch < 4; ++ch) {
            const float* src = z + (((size_t)(bz * 256 + ch * 64 + c)) << 10) + hw0 + hwo;
            float vv[16];
            *(f32x4*)&vv[0]  = *(const f32x4*)(src);
            *(f32x4*)&vv[4]  = *(const f32x4*)(src + 4);
            *(f32x4*)&vv[8]  = *(const f32x4*)(src + 8);
            *(f32x4*)&vv[12] = *(const f32x4*)(src + 12);
#pragma unroll
            for (int j = 0; j < 16; ++j) {
                __bf16 h = (__bf16)vv[j];
                xa[hwo + j][ch * 64 + c] = *(const u16*)&h;
            }
        }
    }
    __syncthreads();

    float wmin[4][4];
#pragma unroll
    for (int mi = 0; mi < 4; ++mi)
#pragma unroll
        for (int r = 0; r < 4; ++r) wmin[mi][r] = 3.4e38f;

    // staging geometry: thread covers LDS floats (i*1024 + w*256 + lane*4 ..+3)
    // = local row (i*32 + w*8 + lane>>3), storage slot (lane&7). Source is
    // pre-swizzled so a read of storage slot s^(row&7) yields logical slot s.
    const int lrow8 = w * 8 + (lane >> 3);          // row within 32-row band
    const int kpart = (lane & 7) * 4;               // linear dest slot (floats)
    const int sw_ld = (lane >> 3) << 2;             // source swizzle (floats)

    for (int it = 0; it < 8; ++it) {
        const int n0w = nb + it * 256 + w * 64;     // this wave's 64 rows
        f32x4 acc[4][4];
        float en_acc[4] = {0.f, 0.f, 0.f, 0.f};
#pragma unroll
        for (int mi = 0; mi < 4; ++mi)
#pragma unroll
            for (int ni = 0; ni < 4; ++ni) {
                f32x4 zz = {0.f, 0.f, 0.f, 0.f};
                acc[mi][ni] = zz;
            }
        for (int k0 = 0; k0 < 8; ++k0) {
            __syncthreads();            // previous chunk fully consumed
#pragma unroll
            for (int i = 0; i < 8; ++i) {
                const float* src = cb
                    + (((size_t)(nb + it * 256 + i * 32 + lrow8)) << 8)
                    + k0 * 32 + (kpart ^ sw_ld);
                __builtin_amdgcn_global_load_lds(
                    (glb_f*)src, (lds_f*)(bsf + i * 1024 + w * 256), 16, 0, 0);
            }
            __syncthreads();            // staged; compiler drains vmcnt here
            // compute: swizzled ds_read_b128, squares for ||e||^2, cvt, MFMA
            bf16x8 fb[4];
#pragma unroll
            for (int ni = 0; ni < 4; ++ni) {
                const int lr = w * 64 + ni * 16 + r16;
                const int s0 = ((kg * 2 + 0) ^ (r16 & 7)) * 4;
                const int s1 = ((kg * 2 + 1) ^ (r16 & 7)) * 4;
                f32x4 lo = *(const f32x4*)&bsf[lr * 32 + s0];
                f32x4 hi = *(const f32x4*)&bsf[lr * 32 + s1];
#pragma unroll
                for (int j = 0; j < 4; ++j)
                    en_acc[ni] += lo[j] * lo[j] + hi[j] * hi[j];
                bf16x8 f;
                f[0] = (__bf16)lo[0]; f[1] = (__bf16)lo[1];
                f[2] = (__bf16)lo[2]; f[3] = (__bf16)lo[3];
                f[4] = (__bf16)hi[0]; f[5] = (__bf16)hi[1];
                f[6] = (__bf16)hi[2]; f[7] = (__bf16)hi[3];
                fb[ni] = f;
            }
            bf16x8 fa[4];
#pragma unroll
            for (int mi = 0; mi < 4; ++mi)
                fa[mi] = *(const bf16x8*)&xa[r16 + mi * 16][kg * 8 + k0 * 32];
#pragma unroll
            for (int mi = 0; mi < 4; ++mi)
#pragma unroll
                for (int ni = 0; ni < 4; ++ni)
                    acc[mi][ni] = __builtin_amdgcn_mfma_f32_16x16x32_bf16(
                            fa[mi], fb[ni], acc[mi][ni], 0, 0, 0);
        }
        // finish ||e||^2: sum the 4 kg-slices (lanes r16, +16, +32, +48)
        float en[4];
#pragma unroll
        for (int ni = 0; ni < 4; ++ni) {
            float e = en_acc[ni];
            e += __shfl_xor(e, 16);
            e += __shfl_xor(e, 32);
            en[ni] = e;
        }
        // scores: s = ||e||^2 - 2*dot  (row-constant ||x||^2 dropped)
#pragma unroll
        for (int ni = 0; ni < 4; ++ni)
#pragma unroll
            for (int mi = 0; mi < 4; ++mi)
#pragma unroll
                for (int r = 0; r < 4; ++r)
                    acc[mi][ni][r] = en[ni] - 2.0f * acc[mi][ni][r];
        // tile min -> cross-wave LDS rowmin (running mins only decrease:
        // threshold stays a safe superset without barriers)
#pragma unroll
        for (int mi = 0; mi < 4; ++mi)
#pragma unroll
            for (int r = 0; r < 4; ++r) {
                float v = fminf(fminf(acc[mi][0][r], acc[mi][1][r]),
                                fminf(acc[mi][2][r], acc[mi][3][r]));
#pragma unroll
                for (int d = 1; d < 16; d <<= 1)
                    v = fminf(v, __shfl_xor(v, d));
                const float wm = fminf(wmin[mi][r], v);
                wmin[mi][r] = wm;
                if (r16 == 0)
                    atomicMin(&rowmin_s[mi * 16 + kg * 4 + r], fkey(wm));
            }
        // capture vs min(shared rowmin, own) + DELTA
#pragma unroll
        for (int mi = 0; mi < 4; ++mi)
#pragma unroll
            for (int r = 0; r < 4; ++r) {
                const int ml = mi * 16 + kg * 4 + r;   // D row = (lane>>4)*4+reg
                const float thr = fminf(unfkey(rowmin_s[ml]), wmin[mi][r]) + DELTA;
#pragma unroll
                for (int ni = 0; ni < 4; ++ni) {
                    if (acc[mi][ni][r] <= thr) {
                        int pos = atomicAdd(&cnt[ml], 1);
                        if (pos < 14) candl[ml][pos] = (u32)(n0w + ni * 16 + r16);
                    }
                }
            }
    }
    __syncthreads();
    // write slab [64 rows][16 u32]: {minval, cnt, cand0..cand13}
    {
        const int row_l = tid >> 2, q = tid & 3;
        u32x4 wv;
        if (q == 0) {
            wv[0] = __float_as_uint(unfkey(rowmin_s[row_l]));
            wv[1] = (u32)cnt[row_l];
            wv[2] = candl[row_l][0];
            wv[3] = candl[row_l][1];
        } else {
            const int base = q * 4 - 2;  // 2, 6, 10
            wv[0] = candl[row_l][base];
            wv[1] = candl[row_l][base + 1];
            wv[2] = candl[row_l][base + 2];
            wv[3] = candl[row_l][base + 3];
        }
        u32* dst = cand + ((((size_t)(m0 + row_l)) * 8 + split) << 4) + q * 4;
        *(u32x4*)dst = wv;
    }
}

// ---------- finalize: exact f64 rescore of captured candidates ----------
// grid 1024 x 256: block = 4 consecutive rows, one wave per row; z staged
// cooperatively through LDS.
__global__ __launch_bounds__(256) void finalize(const float* __restrict__ z,
                                                const float* __restrict__ cb,
                                                const u32* __restrict__ cand,
                                                u32* __restrict__ bestn) {
    __shared__ u32 slab[4][128];
    __shared__ float zs[4][260];
    const int tid = threadIdx.x;
    const int w = tid >> 6, lane = tid & 63;
    const int row0 = blockIdx.x * 4;
    const int bz = row0 >> 10, hw0 = row0 & 1023;

    // stage z: thread c=tid loads z[bz][c][hw0..hw0+4) (16 B contiguous)
    {
        f32x4 v = *(const f32x4*)(z + (((size_t)(bz * 256 + tid)) << 10) + hw0);
        zs[0][tid] = v[0]; zs[1][tid] = v[1]; zs[2][tid] = v[2]; zs[3][tid] = v[3];
    }
    if (lane < 32)
        *(u32x4*)&slab[w][lane * 4] =
            *(const u32x4*)(cand + (size_t)(row0 + w) * 128 + lane * 4);
    __syncthreads();

    float xv[4];
    {
        f32x4 xq = *(const f32x4*)&zs[w][lane * 4];
        xv[0] = xq[0]; xv[1] = xq[1]; xv[2] = xq[2]; xv[3] = xq[3];
    }

    // global row min over the 8 splits (LDS broadcast reads)
    float gm = 3.4e38f;
#pragma unroll
    for (int s = 0; s < 8; ++s) gm = fminf(gm, __uint_as_float(slab[w][s * 16]));

    double bs = 1e300;
    int bn = 0x7fffffff;
#define RESCORE(NV)                                                         \
    {                                                                       \
        const int n_ = (NV);                                                \
        f32x4 ev = *(const f32x4*)(cb + (((size_t)n_) << 8) + lane * 4);    \
        double t = 0.0;                                                     \
        _Pragma("unroll")                                                   \
        for (int j = 0; j < 4; ++j) {                                       \
            double dl = (double)xv[j] - (double)ev[j];                      \
            t += dl * dl;                                                   \
        }                                                                   \
        _Pragma("unroll")                                                   \
        for (int d = 1; d < 64; d <<= 1) t += __shfl_xor(t, d);             \
        if (t < bs || (t == bs && n_ < bn)) { bs = t; bn = n_; }            \
    }

    for (int s = 0; s < 8; ++s) {
        const float mvs = __uint_as_float(slab[w][s * 16]);
        if (mvs > gm + DELTA) continue;          // no candidate here can win
        const u32 c = slab[w][s * 16 + 1];
        if (c > 14) {
            // capture overflow (rare): exact scan of this split
            for (int n = s * 2048; n < s * 2048 + 2048; ++n) RESCORE(n);
        } else {
            for (u32 ci = 0; ci < c; ++ci) RESCORE((int)slab[w][s * 16 + 2 + ci]);
        }
    }
#undef RESCORE
    if (lane == 0) bestn[row0 + w] = (u32)bn;
}

// ---------- gather selected codebook rows (f32) into channel-first out ----------
__global__ __launch_bounds__(256) void vq_out(const u32* __restrict__ bestn,
                                              const float* __restrict__ cb,
                                              float* __restrict__ out) {
    __shared__ float rows_l[64][133];
    __shared__ int idx_s[64];
    const int tid = threadIdx.x;
    const int hwt = blockIdx.x, b = blockIdx.y;
    const int m0 = b * 1024 + hwt * 64;
    if (tid < 64) idx_s[tid] = (int)bestn[m0 + tid];
    __syncthreads();
    const int lane = tid & 63, w = tid >> 6;
#pragma unroll
    for (int half = 0; half < 2; ++half) {
        const int row = tid >> 2, q = tid & 3;
        const float* src = cb + (((size_t)idx_s[row]) << 8) + half * 128 + q * 32;
#pragma unroll
        for (int j = 0; j < 8; ++j)
            *(f32x4*)&rows_l[row][q * 32 + j * 4] = *(const f32x4*)(src + j * 4);
        __syncthreads();
#pragma unroll
        for (int i = 0; i < 32; ++i) {
            const int c = half * 128 + w * 32 + i;
            out[(((size_t)(b * 256 + c)) << 10) + hwt * 64 + lane] = rows_l[lane][w * 32 + i];
        }
        __syncthreads();
    }
}

extern "C" void kernel_launch(void* const* d_in, const int* in_sizes, int n_in,
                              void* d_out, int out_size, void* d_ws, size_t ws_size,
                              hipStream_t stream) {
    const float* z   = (const float*)d_in[0];
    const float* cb  = (const float*)d_in[1];
    const float* img = (const float*)d_in[2];
    const float* prm = (const float*)d_in[3];
    float* out = (float*)d_out;

    u32* bestn = (u32*)d_in[2];               // img reused AFTER spherical reads it
    u32* cand = (u32*)d_out;                  // 2 MiB slabs, overwritten by vq_out

    hipMemsetAsync(out + 1048576, 0, 512 * sizeof(float), stream);
    spherical_i<<<32, 512, 0, stream>>>(img, prm, out + 1048576);
    sweep<<<512, 256, 0, stream>>>(z, cb, cand);
    finalize<<<1024, 256, 0, stream>>>(z, cb, cand, bestn);
    vq_out<<<dim3(16, 4), 256, 0, stream>>>(bestn, cb, out);
}